// Round 1
// baseline (60.709 us; speedup 1.0000x reference)
//
#include <hip/hip_runtime.h>
#include <hip/hip_bf16.h>

// LocalAttention: B=2, S=2048, E=256, pad=128, W=257 (no masking of padded
// positions: k_ext/v_ext in pad region = bias).
//
// Pipeline (all bf16 MFMA, fp32 accum; threshold is 2% of ref absmax):
//   prep: W (3x256x256 f32) -> W_T bf16 [768][256] (transposed), bias f32 [768]
//   proj: Y = x_ext @ [Wq|Wk|Wv] + b  -> Q_ext, K_ext row-major bf16 [REXT][256],
//         V_T transposed bf16 [256][REXT]   (REXT=2368 padded ext rows per batch)
//   attn: 1 wave per 16-query tile; energy QK^T via mfma_16x16x32_bf16,
//         softmax through LDS, PV via mfma with A=P (LDS), B=V_T (global/L2).

#define SQ    2048
#define EMB   256
#define PADP  128
#define REXT  2368   // 2304 ext rows + 64 pad (PV overreach + tile rounding)
#define NB    2

typedef __bf16 bf16;
typedef __bf16 bf16x8 __attribute__((ext_vector_type(8)));
typedef float  f32x4  __attribute__((ext_vector_type(4)));

__device__ __forceinline__ bf16x8 cvt8(const float4& a, const float4& b) {
  bf16x8 r;
  r[0] = (__bf16)a.x; r[1] = (__bf16)a.y; r[2] = (__bf16)a.z; r[3] = (__bf16)a.w;
  r[4] = (__bf16)b.x; r[5] = (__bf16)b.y; r[6] = (__bf16)b.z; r[7] = (__bf16)b.w;
  return r;
}

// ---------------------------------------------------------------- prep ------
// blocks 0..47: 64x64 transpose tiles of Wq/Wk/Wv -> W_T[n][k] bf16.
// block 48: bias concat.
__global__ __launch_bounds__(256) void prep_kernel(
    const float* __restrict__ Wq, const float* __restrict__ bq,
    const float* __restrict__ Wk, const float* __restrict__ bk,
    const float* __restrict__ Wv, const float* __restrict__ bv,
    bf16* __restrict__ W_T, float* __restrict__ bias) {
  int bx = blockIdx.x;
  int tid = threadIdx.x;
  if (bx == 48) {
    bias[tid]       = bq[tid];
    bias[256 + tid] = bk[tid];
    bias[512 + tid] = bv[tid];
    return;
  }
  __shared__ float lds[64][65];
  int mat = bx >> 4, tile = bx & 15;
  int tr = tile >> 2, tc = tile & 3;
  const float* W = (mat == 0) ? Wq : (mat == 1) ? Wk : Wv;
  int c = tid & 63, rbase = tid >> 6;  // rbase 0..3
#pragma unroll
  for (int i = 0; i < 16; i++) {
    int r = rbase + i * 4;
    lds[r][c] = W[(size_t)(tr * 64 + r) * 256 + tc * 64 + c];
  }
  __syncthreads();
#pragma unroll
  for (int i = 0; i < 16; i++) {
    int r = rbase + i * 4;  // output row within tile (n-local)
    W_T[(size_t)(mat * 256 + tc * 64 + r) * 256 + tr * 64 + c] = (bf16)lds[c][r];
  }
}

// ---------------------------------------------------------------- proj ------
// grid (74, 12): x -> (b, row-tile of 64), y -> 64-col tile of 768.
// 4 waves, each owns a 16-row m-tile; register-only MFMA (K=256 = 8 chunks).
__global__ __launch_bounds__(256) void proj_kernel(
    const float* __restrict__ x, const bf16* __restrict__ W_T,
    const float* __restrict__ bias, bf16* __restrict__ Qext,
    bf16* __restrict__ Kext, bf16* __restrict__ Vt) {
  int wave = threadIdx.x >> 6, lane = threadIdx.x & 63;
  int lrow = lane & 15, lgrp = lane >> 4;
  int b = blockIdx.x / 37, rt = blockIdx.x % 37;
  int row_base = rt * 64 + wave * 16;   // ext row base of this wave's m-tile
  int r_ext = row_base + lrow;          // A-frag row (m = lane%16)
  int s = r_ext - PADP;                 // source row in x
  bool inx = (s >= 0) && (s < SQ);
  const float* xrow = x + ((size_t)b * SQ + (size_t)(inx ? s : 0)) * EMB;

  bf16x8 af[8];
#pragma unroll
  for (int kc = 0; kc < 8; kc++) {
    int k0 = kc * 32 + lgrp * 8;
    if (inx) {
      float4 f0 = *(const float4*)(xrow + k0);
      float4 f1 = *(const float4*)(xrow + k0 + 4);
      af[kc] = cvt8(f0, f1);
    } else {
#pragma unroll
      for (int j = 0; j < 8; j++) af[kc][j] = (__bf16)0.f;
    }
  }

  int seg = blockIdx.y >> 2;  // 0=Q 1=K 2=V
  __shared__ float vt[4][16][17];

  for (int nt = 0; nt < 4; nt++) {
    int n = blockIdx.y * 64 + nt * 16 + lrow;  // B-frag col (lane%16)
    const bf16* wrow = W_T + (size_t)n * 256;
    f32x4 acc;
#pragma unroll
    for (int j = 0; j < 4; j++) acc[j] = 0.f;
#pragma unroll
    for (int kc = 0; kc < 8; kc++) {
      bf16x8 bf = *(const bf16x8*)(wrow + kc * 32 + lgrp * 8);
      acc = __builtin_amdgcn_mfma_f32_16x16x32_bf16(af[kc], bf, acc, 0, 0, 0);
    }
    float bs = bias[n];
    if (seg < 2) {
      bf16* dst = (seg == 0 ? Qext : Kext) + (size_t)b * REXT * EMB;
      int nl = n - seg * 256;
#pragma unroll
      for (int r = 0; r < 4; r++) {
        int grow = row_base + 4 * lgrp + r;  // C row m = 4*(lane/16)+r
        dst[(size_t)grow * EMB + nl] = (bf16)(acc[r] + bs);
      }
    } else {
      // V: bounce 16x16 tile through LDS, store transposed V_T[n][row]
      __syncthreads();
#pragma unroll
      for (int r = 0; r < 4; r++) vt[wave][4 * lgrp + r][lrow] = acc[r] + bs;
      __syncthreads();
      bf16* dst = Vt + (size_t)b * 256 * REXT;
#pragma unroll
      for (int j = 0; j < 4; j++) {
        int nl16 = lgrp + 4 * j;
        int nl = (blockIdx.y - 8) * 64 + nt * 16 + nl16;
        dst[(size_t)nl * REXT + row_base + lrow] = (bf16)vt[wave][lrow][nl16];
      }
    }
  }
}

// ---------------------------------------------------------------- attn ------
// grid (128, 2), block 64 (1 wave). Tile = 16 queries, key window union = 272.
__global__ __launch_bounds__(64) void attn_kernel(
    const bf16* __restrict__ Qext, const bf16* __restrict__ Kext,
    const bf16* __restrict__ Vt, float* __restrict__ out) {
  __shared__ float e_lds[16][273];              // stride 273 words (odd) -> no conflicts
  __shared__ __align__(16) bf16 p_lds[16][296]; // stride 148 words = 4*37 -> 2-way max
  __shared__ float rsum_lds[16];
  int lane = threadIdx.x;
  int lrow = lane & 15, lgrp = lane >> 4;
  int b = blockIdx.y;
  int s0 = blockIdx.x * 16;  // query tile start; ext-key base is also s0

  const bf16* Q = Qext + (size_t)b * REXT * EMB;
  const bf16* K = Kext + (size_t)b * REXT * EMB;
  const bf16* V = Vt + (size_t)b * 256 * REXT;

  // Q fragments (A operand, row = query = lane%16), cached for all 17 tiles
  bf16x8 qf[8];
  const bf16* qrow = Q + (size_t)(s0 + PADP + lrow) * EMB;
#pragma unroll
  for (int kc = 0; kc < 8; kc++) qf[kc] = *(const bf16x8*)(qrow + kc * 32 + lgrp * 8);

  // ---- energies: S[q][t] = Q·K^T / 16, masked to band t in [q, q+256]
  for (int tile = 0; tile < 17; tile++) {
    f32x4 acc;
#pragma unroll
    for (int j = 0; j < 4; j++) acc[j] = 0.f;
    const bf16* krow = K + (size_t)(s0 + tile * 16 + lrow) * EMB;  // B col = key
#pragma unroll
    for (int kc = 0; kc < 8; kc++) {
      bf16x8 kf = *(const bf16x8*)(krow + kc * 32 + lgrp * 8);
      acc = __builtin_amdgcn_mfma_f32_16x16x32_bf16(qf[kc], kf, acc, 0, 0, 0);
    }
    int t = tile * 16 + lrow;  // C col = key t
#pragma unroll
    for (int r = 0; r < 4; r++) {
      int q = 4 * lgrp + r;    // C row = query
      bool valid = (t >= q) && (t <= q + 256);
      e_lds[q][t] = valid ? acc[r] * 0.0625f : -1e30f;
    }
  }
  __syncthreads();

  // ---- softmax: lane -> (q = lane%16, part = lane/16 covers 68 keys)
  {
    int q = lrow, part = lgrp;
    float m = -1e30f;
    for (int i = 0; i < 68; i++) m = fmaxf(m, e_lds[q][part * 68 + i]);
    m = fmaxf(m, __shfl_xor(m, 16));
    m = fmaxf(m, __shfl_xor(m, 32));
    float ps = 0.f;
    for (int i = 0; i < 68; i++) {
      int t = part * 68 + i;
      float p = __expf(e_lds[q][t] - m);
      ps += p;
      p_lds[q][t] = (bf16)p;
    }
    ps += __shfl_xor(ps, 16);
    ps += __shfl_xor(ps, 32);
    if (part == 0) rsum_lds[q] = 1.f / ps;
#pragma unroll
    for (int j = 0; j < 6; j++) p_lds[q][272 + part * 6 + j] = (__bf16)0.f;  // PV pad
  }
  __syncthreads();

  // ---- PV: out[q][e] = P (16x288) @ V (288x256); A=P from LDS, B from V_T
  f32x4 acc[16];
#pragma unroll
  for (int nt = 0; nt < 16; nt++)
#pragma unroll
    for (int j = 0; j < 4; j++) acc[nt][j] = 0.f;

  for (int kc = 0; kc < 9; kc++) {
    bf16x8 pf = *(const bf16x8*)(&p_lds[lrow][kc * 32 + lgrp * 8]);  // A row=q
    size_t vcol = (size_t)(s0 + kc * 32 + lgrp * 8);
#pragma unroll
    for (int nt = 0; nt < 16; nt++) {
      const bf16* vrow = V + (size_t)(nt * 16 + lrow) * REXT + vcol;  // B col=e
      bf16x8 vf = *(const bf16x8*)vrow;
      acc[nt] = __builtin_amdgcn_mfma_f32_16x16x32_bf16(pf, vf, acc[nt], 0, 0, 0);
    }
  }

  float* orow = out + ((size_t)b * SQ + s0) * EMB;
#pragma unroll
  for (int nt = 0; nt < 16; nt++) {
#pragma unroll
    for (int r = 0; r < 4; r++) {
      int q = 4 * lgrp + r;                       // C row = query
      float sc = rsum_lds[q];
      orow[(size_t)q * EMB + nt * 16 + lrow] = acc[nt][r] * sc;  // C col = e
    }
  }
}

// -------------------------------------------------------------- launch ------
extern "C" void kernel_launch(void* const* d_in, const int* in_sizes, int n_in,
                              void* d_out, int out_size, void* d_ws, size_t ws_size,
                              hipStream_t stream) {
  const float* x  = (const float*)d_in[0];
  const float* Wq = (const float*)d_in[1];
  const float* bq = (const float*)d_in[2];
  const float* Wk = (const float*)d_in[3];
  const float* bk = (const float*)d_in[4];
  const float* Wv = (const float*)d_in[5];
  const float* bv = (const float*)d_in[6];
  float* out = (float*)d_out;

  char* ws = (char*)d_ws;
  // ws layout (bytes): W_T bf16 768*256*2=393216 | bias f32 768*4=3072 |
  //                    Q_ext | K_ext | V_T  (each 2*2368*256*2 = 2424832)
  bf16* W_T   = (bf16*)(ws);
  float* bias = (float*)(ws + 393216);
  bf16* Qext  = (bf16*)(ws + 396288);
  bf16* Kext  = (bf16*)(ws + 396288 + 2424832);
  bf16* Vt    = (bf16*)(ws + 396288 + 2u * 2424832);
  // total ws use: 7,670,784 bytes

  prep_kernel<<<49, 256, 0, stream>>>(Wq, bq, Wk, bk, Wv, bv, W_T, bias);
  proj_kernel<<<dim3(74, 12), 256, 0, stream>>>(x, W_T, bias, Qext, Kext, Vt);
  attn_kernel<<<dim3(128, 2), 64, 0, stream>>>(Qext, Kext, Vt, out);
}

// Round 2
// 49.738 us; speedup vs baseline: 1.2206x; 1.2206x over previous
//
#include <hip/hip_runtime.h>
#include <hip/hip_bf16.h>

// LocalAttention: B=2, S=2048, E=256, pad=128, W=257 (no masking of padded
// positions: k_ext/v_ext in pad region = bias).
//
// Pipeline (all bf16 MFMA, fp32 accum):
//   prep: W (3x256x256 f32) -> W_T bf16 [768][256] (transposed), bias f32 [768]
//   proj: Y = x_ext @ [Wq|Wk|Wv] + b  -> Q_ext, K_ext row-major bf16 [REXT][256],
//         V_T transposed bf16 [256][REXT]   (REXT=2368 padded ext rows per batch)
//   attn: 4 waves per 16-query tile (energy tiles / softmax parts / PV columns
//         split across waves); QK^T and PV via mfma_16x16x32_bf16.

#define SQ    2048
#define EMB   256
#define PADP  128
#define REXT  2368   // 2304 ext rows + 64 pad (PV overreach + tile rounding)
#define NB    2

typedef __bf16 bf16;
typedef __bf16 bf16x8 __attribute__((ext_vector_type(8)));
typedef float  f32x4  __attribute__((ext_vector_type(4)));

__device__ __forceinline__ bf16x8 cvt8(const float4& a, const float4& b) {
  bf16x8 r;
  r[0] = (__bf16)a.x; r[1] = (__bf16)a.y; r[2] = (__bf16)a.z; r[3] = (__bf16)a.w;
  r[4] = (__bf16)b.x; r[5] = (__bf16)b.y; r[6] = (__bf16)b.z; r[7] = (__bf16)b.w;
  return r;
}

// ---------------------------------------------------------------- prep ------
__global__ __launch_bounds__(256) void prep_kernel(
    const float* __restrict__ Wq, const float* __restrict__ bq,
    const float* __restrict__ Wk, const float* __restrict__ bk,
    const float* __restrict__ Wv, const float* __restrict__ bv,
    bf16* __restrict__ W_T, float* __restrict__ bias) {
  int bx = blockIdx.x;
  int tid = threadIdx.x;
  if (bx == 48) {
    bias[tid]       = bq[tid];
    bias[256 + tid] = bk[tid];
    bias[512 + tid] = bv[tid];
    return;
  }
  __shared__ float lds[64][65];
  int mat = bx >> 4, tile = bx & 15;
  int tr = tile >> 2, tc = tile & 3;
  const float* W = (mat == 0) ? Wq : (mat == 1) ? Wk : Wv;
  int c = tid & 63, rbase = tid >> 6;
#pragma unroll
  for (int i = 0; i < 16; i++) {
    int r = rbase + i * 4;
    lds[r][c] = W[(size_t)(tr * 64 + r) * 256 + tc * 64 + c];
  }
  __syncthreads();
#pragma unroll
  for (int i = 0; i < 16; i++) {
    int r = rbase + i * 4;
    W_T[(size_t)(mat * 256 + tc * 64 + r) * 256 + tr * 64 + c] = (bf16)lds[c][r];
  }
}

// ---------------------------------------------------------------- proj ------
__global__ __launch_bounds__(256) void proj_kernel(
    const float* __restrict__ x, const bf16* __restrict__ W_T,
    const float* __restrict__ bias, bf16* __restrict__ Qext,
    bf16* __restrict__ Kext, bf16* __restrict__ Vt) {
  int wave = threadIdx.x >> 6, lane = threadIdx.x & 63;
  int lrow = lane & 15, lgrp = lane >> 4;
  int b = blockIdx.x / 37, rt = blockIdx.x % 37;
  int row_base = rt * 64 + wave * 16;
  int r_ext = row_base + lrow;
  int s = r_ext - PADP;
  bool inx = (s >= 0) && (s < SQ);
  const float* xrow = x + ((size_t)b * SQ + (size_t)(inx ? s : 0)) * EMB;

  bf16x8 af[8];
#pragma unroll
  for (int kc = 0; kc < 8; kc++) {
    int k0 = kc * 32 + lgrp * 8;
    if (inx) {
      float4 f0 = *(const float4*)(xrow + k0);
      float4 f1 = *(const float4*)(xrow + k0 + 4);
      af[kc] = cvt8(f0, f1);
    } else {
#pragma unroll
      for (int j = 0; j < 8; j++) af[kc][j] = (__bf16)0.f;
    }
  }

  int seg = blockIdx.y >> 2;  // 0=Q 1=K 2=V
  __shared__ float vt[4][16][17];

  for (int nt = 0; nt < 4; nt++) {
    int n = blockIdx.y * 64 + nt * 16 + lrow;
    const bf16* wrow = W_T + (size_t)n * 256;
    f32x4 acc;
#pragma unroll
    for (int j = 0; j < 4; j++) acc[j] = 0.f;
#pragma unroll
    for (int kc = 0; kc < 8; kc++) {
      bf16x8 bf = *(const bf16x8*)(wrow + kc * 32 + lgrp * 8);
      acc = __builtin_amdgcn_mfma_f32_16x16x32_bf16(af[kc], bf, acc, 0, 0, 0);
    }
    float bs = bias[n];
    if (seg < 2) {
      bf16* dst = (seg == 0 ? Qext : Kext) + (size_t)b * REXT * EMB;
      int nl = n - seg * 256;
#pragma unroll
      for (int r = 0; r < 4; r++) {
        int grow = row_base + 4 * lgrp + r;
        dst[(size_t)grow * EMB + nl] = (bf16)(acc[r] + bs);
      }
    } else {
      __syncthreads();
#pragma unroll
      for (int r = 0; r < 4; r++) vt[wave][4 * lgrp + r][lrow] = acc[r] + bs;
      __syncthreads();
      bf16* dst = Vt + (size_t)b * 256 * REXT;
#pragma unroll
      for (int j = 0; j < 4; j++) {
        int nl16 = lgrp + 4 * j;
        int nl = (blockIdx.y - 8) * 64 + nt * 16 + nl16;
        dst[(size_t)nl * REXT + row_base + lrow] = (bf16)vt[wave][lrow][nl16];
      }
    }
  }
}

// ---------------------------------------------------------------- attn ------
// grid (128, 2), block 256 = 4 waves cooperating on ONE 16-query tile.
//   energy: wave w does key-tiles {w, w+4, ...} of 17
//   softmax: 256 threads -> (q = tid%16, part = tid/16), 17 keys/part
//   PV: wave w does e-column tiles {4w .. 4w+3} of 16
__global__ __launch_bounds__(256) void attn_kernel(
    const bf16* __restrict__ Qext, const bf16* __restrict__ Kext,
    const bf16* __restrict__ Vt, float* __restrict__ out) {
  __shared__ float e_lds[16][273];              // 273 words odd -> conflict-free rows
  __shared__ __align__(16) bf16 p_lds[16][296]; // stride 148 words -> 2-way max
  __shared__ float wred[16][4];
  __shared__ float wsum[16][4];
  __shared__ float rsum_lds[16];
  int tid = threadIdx.x;
  int wave = tid >> 6, lane = tid & 63;
  int lrow = lane & 15, lgrp = lane >> 4;
  int b = blockIdx.y;
  int s0 = blockIdx.x * 16;  // query tile start; ext-key base is also s0

  const bf16* Q = Qext + (size_t)b * REXT * EMB;
  const bf16* K = Kext + (size_t)b * REXT * EMB;
  const bf16* V = Vt + (size_t)b * 256 * REXT;

  // Q fragments (A operand, row = query = lane%16); same in all 4 waves
  bf16x8 qf[8];
  const bf16* qrow = Q + (size_t)(s0 + PADP + lrow) * EMB;
#pragma unroll
  for (int kc = 0; kc < 8; kc++) qf[kc] = *(const bf16x8*)(qrow + kc * 32 + lgrp * 8);

  // ---- energies: S[q][t] = Q·K^T / 16, masked to band t in [q, q+256]
  for (int tile = wave; tile < 17; tile += 4) {
    f32x4 acc;
#pragma unroll
    for (int j = 0; j < 4; j++) acc[j] = 0.f;
    const bf16* krow = K + (size_t)(s0 + tile * 16 + lrow) * EMB;
#pragma unroll
    for (int kc = 0; kc < 8; kc++) {
      bf16x8 kf = *(const bf16x8*)(krow + kc * 32 + lgrp * 8);
      acc = __builtin_amdgcn_mfma_f32_16x16x32_bf16(qf[kc], kf, acc, 0, 0, 0);
    }
    int t = tile * 16 + lrow;
#pragma unroll
    for (int r = 0; r < 4; r++) {
      int q = 4 * lgrp + r;
      bool valid = (t >= q) && (t <= q + 256);
      e_lds[q][t] = valid ? acc[r] * 0.0625f : -1e30f;
    }
  }
  __syncthreads();

  // ---- softmax
  {
    int q = tid & 15, part = tid >> 4;       // part 0..15, keys [17*part, 17*part+17)
    const float* erow = &e_lds[q][part * 17];
    float m = -1e30f;
#pragma unroll
    for (int i = 0; i < 17; i++) m = fmaxf(m, erow[i]);
    m = fmaxf(m, __shfl_xor(m, 16));
    m = fmaxf(m, __shfl_xor(m, 32));         // max over the 4 parts in this wave
    if (lane < 16) wred[q][wave] = m;        // lane<16 => q==lane, part%4==0
    __syncthreads();
    m = fmaxf(fmaxf(wred[q][0], wred[q][1]), fmaxf(wred[q][2], wred[q][3]));
    float ps = 0.f;
#pragma unroll
    for (int i = 0; i < 17; i++) {
      float p = __expf(erow[i] - m);
      ps += p;
      p_lds[q][part * 17 + i] = (bf16)p;
    }
    ps += __shfl_xor(ps, 16);
    ps += __shfl_xor(ps, 32);
    if (lane < 16) wsum[q][wave] = ps;
    p_lds[q][272 + part] = (__bf16)0.f;      // zero-pad keys [272,288) for PV
    __syncthreads();
    if (tid < 16) {
      float t = (wsum[tid][0] + wsum[tid][1]) + (wsum[tid][2] + wsum[tid][3]);
      rsum_lds[tid] = 1.f / t;
    }
    __syncthreads();
  }

  // ---- PV: out[q][e] = P (16x288) @ V (288x256); wave w -> e-tiles 4w..4w+3
  f32x4 acc[4];
#pragma unroll
  for (int nt = 0; nt < 4; nt++)
#pragma unroll
    for (int j = 0; j < 4; j++) acc[nt][j] = 0.f;

  for (int kc = 0; kc < 9; kc++) {
    bf16x8 pf = *(const bf16x8*)(&p_lds[lrow][kc * 32 + lgrp * 8]);  // A row=q
    size_t vcol = (size_t)(s0 + kc * 32 + lgrp * 8);
#pragma unroll
    for (int nt = 0; nt < 4; nt++) {
      int e0 = (wave * 4 + nt) * 16 + lrow;                          // B col=e
      const bf16* vrow = V + (size_t)e0 * REXT + vcol;
      bf16x8 vf = *(const bf16x8*)vrow;
      acc[nt] = __builtin_amdgcn_mfma_f32_16x16x32_bf16(pf, vf, acc[nt], 0, 0, 0);
    }
  }

  float* orow = out + ((size_t)b * SQ + s0) * EMB;
#pragma unroll
  for (int nt = 0; nt < 4; nt++) {
#pragma unroll
    for (int r = 0; r < 4; r++) {
      int q = 4 * lgrp + r;
      float sc = rsum_lds[q];
      orow[(size_t)q * EMB + (wave * 4 + nt) * 16 + lrow] = acc[nt][r] * sc;
    }
  }
}

// -------------------------------------------------------------- launch ------
extern "C" void kernel_launch(void* const* d_in, const int* in_sizes, int n_in,
                              void* d_out, int out_size, void* d_ws, size_t ws_size,
                              hipStream_t stream) {
  const float* x  = (const float*)d_in[0];
  const float* Wq = (const float*)d_in[1];
  const float* bq = (const float*)d_in[2];
  const float* Wk = (const float*)d_in[3];
  const float* bk = (const float*)d_in[4];
  const float* Wv = (const float*)d_in[5];
  const float* bv = (const float*)d_in[6];
  float* out = (float*)d_out;

  char* ws = (char*)d_ws;
  bf16* W_T   = (bf16*)(ws);
  float* bias = (float*)(ws + 393216);
  bf16* Qext  = (bf16*)(ws + 396288);
  bf16* Kext  = (bf16*)(ws + 396288 + 2424832);
  bf16* Vt    = (bf16*)(ws + 396288 + 2u * 2424832);

  prep_kernel<<<49, 256, 0, stream>>>(Wq, bq, Wk, bk, Wv, bv, W_T, bias);
  proj_kernel<<<dim3(74, 12), 256, 0, stream>>>(x, W_T, bias, Qext, Kext, Vt);
  attn_kernel<<<dim3(128, 2), 256, 0, stream>>>(Qext, Kext, Vt, out);
}

// Round 3
// 45.439 us; speedup vs baseline: 1.3361x; 1.0946x over previous
//
#include <hip/hip_runtime.h>
#include <hip/hip_bf16.h>

// LocalAttention: B=2, S=2048, E=256, pad=128, W=257.
// prep: W -> W_T bf16 [768][256], bias f32 [768]
// proj: Q_ext/K_ext row-major bf16 [REXT][256]; V_T bf16 [256][REXT]
// attn: 4 waves/16-query tile; V window async-staged to LDS (swizzled),
//       K depth-3 reg prefetch, in-register softmax, PV from LDS.

#define SQ    2048
#define EMB   256
#define PADP  128
#define REXT  2368
#define PSTR  296

typedef __bf16 bf16;
typedef __bf16 bf16x8 __attribute__((ext_vector_type(8)));
typedef float  f32x4  __attribute__((ext_vector_type(4)));

#define MFMA16(a, b, c) __builtin_amdgcn_mfma_f32_16x16x32_bf16(a, b, c, 0, 0, 0)

__device__ __forceinline__ bf16x8 cvt8(const float4& a, const float4& b) {
  bf16x8 r;
  r[0] = (__bf16)a.x; r[1] = (__bf16)a.y; r[2] = (__bf16)a.z; r[3] = (__bf16)a.w;
  r[4] = (__bf16)b.x; r[5] = (__bf16)b.y; r[6] = (__bf16)b.z; r[7] = (__bf16)b.w;
  return r;
}

// ---------------------------------------------------------------- prep ------
__global__ __launch_bounds__(256) void prep_kernel(
    const float* __restrict__ Wq, const float* __restrict__ bq,
    const float* __restrict__ Wk, const float* __restrict__ bk,
    const float* __restrict__ Wv, const float* __restrict__ bv,
    bf16* __restrict__ W_T, float* __restrict__ bias) {
  int bx = blockIdx.x;
  int tid = threadIdx.x;
  if (bx == 48) {
    bias[tid]       = bq[tid];
    bias[256 + tid] = bk[tid];
    bias[512 + tid] = bv[tid];
    return;
  }
  __shared__ float lds[64][65];
  int mat = bx >> 4, tile = bx & 15;
  int tr = tile >> 2, tc = tile & 3;
  const float* W = (mat == 0) ? Wq : (mat == 1) ? Wk : Wv;
  int c = tid & 63, rbase = tid >> 6;
#pragma unroll
  for (int i = 0; i < 16; i++) {
    int r = rbase + i * 4;
    lds[r][c] = W[(size_t)(tr * 64 + r) * 256 + tc * 64 + c];
  }
  __syncthreads();
#pragma unroll
  for (int i = 0; i < 16; i++) {
    int r = rbase + i * 4;
    W_T[(size_t)(mat * 256 + tc * 64 + r) * 256 + tr * 64 + c] = (bf16)lds[c][r];
  }
}

// ---------------------------------------------------------------- proj ------
// grid (74, 6): x -> (b, 64-row tile); y -> seg(0..2) x colhalf(0..1).
__global__ __launch_bounds__(256) void proj_kernel(
    const float* __restrict__ x, const bf16* __restrict__ W_T,
    const float* __restrict__ bias, bf16* __restrict__ Qext,
    bf16* __restrict__ Kext, bf16* __restrict__ Vt) {
  int wave = threadIdx.x >> 6, lane = threadIdx.x & 63;
  int lrow = lane & 15, lgrp = lane >> 4;
  int b = blockIdx.x / 37, rt = blockIdx.x % 37;
  int seg = blockIdx.y >> 1;
  int colbase = (blockIdx.y & 1) * 128;
  int row_base = rt * 64 + wave * 16;
  int r_ext = row_base + lrow;
  int s = r_ext - PADP;
  bool inx = (s >= 0) && (s < SQ);
  const float* xrow = x + ((size_t)b * SQ + (size_t)(inx ? s : 0)) * EMB;

  bf16x8 af[8];
#pragma unroll
  for (int kc = 0; kc < 8; kc++) {
    int k0 = kc * 32 + lgrp * 8;
    if (inx) {
      float4 f0 = *(const float4*)(xrow + k0);
      float4 f1 = *(const float4*)(xrow + k0 + 4);
      af[kc] = cvt8(f0, f1);
    } else {
#pragma unroll
      for (int j = 0; j < 8; j++) af[kc][j] = (__bf16)0.f;
    }
  }

  __shared__ float vt[4][16][17];
  const bf16* wbase = W_T + ((size_t)(seg * 256 + colbase + lrow)) * 256 + lgrp * 8;
  bf16* dstQK = (seg == 0 ? Qext : Kext) + (size_t)b * REXT * EMB;
  bf16* dstV  = Vt + (size_t)b * 256 * REXT;

#define LOADW(dst, nt) { const bf16* wp = wbase + (size_t)(nt) * 16 * 256; \
  _Pragma("unroll") for (int kc = 0; kc < 8; kc++) dst[kc] = *(const bf16x8*)(wp + kc * 32); }

#define PROJSTEP(WC, WN, nt) { \
  if ((nt) < 7) LOADW(WN, (nt) + 1); \
  f32x4 a0 = {0.f, 0.f, 0.f, 0.f}, a1 = {0.f, 0.f, 0.f, 0.f}; \
  a0 = MFMA16(af[0], WC[0], a0); a1 = MFMA16(af[1], WC[1], a1); \
  a0 = MFMA16(af[2], WC[2], a0); a1 = MFMA16(af[3], WC[3], a1); \
  a0 = MFMA16(af[4], WC[4], a0); a1 = MFMA16(af[5], WC[5], a1); \
  a0 = MFMA16(af[6], WC[6], a0); a1 = MFMA16(af[7], WC[7], a1); \
  int nl = colbase + (nt) * 16 + lrow; \
  float bs = bias[seg * 256 + nl]; \
  if (seg < 2) { \
    _Pragma("unroll") for (int r = 0; r < 4; r++) \
      dstQK[(size_t)(row_base + 4 * lgrp + r) * EMB + nl] = (bf16)(a0[r] + a1[r] + bs); \
  } else { \
    __syncthreads(); \
    _Pragma("unroll") for (int r = 0; r < 4; r++) vt[wave][4 * lgrp + r][lrow] = a0[r] + a1[r] + bs; \
    __syncthreads(); \
    _Pragma("unroll") for (int j = 0; j < 4; j++) { \
      int nl16 = lgrp + 4 * j; \
      int nn = colbase + (nt) * 16 + nl16; \
      dstV[(size_t)nn * REXT + row_base + lrow] = (bf16)vt[wave][lrow][nl16]; \
    } \
  } }

  bf16x8 wA[8], wB[8];
  LOADW(wA, 0);
  PROJSTEP(wA, wB, 0); PROJSTEP(wB, wA, 1); PROJSTEP(wA, wB, 2); PROJSTEP(wB, wA, 3);
  PROJSTEP(wA, wB, 4); PROJSTEP(wB, wA, 5); PROJSTEP(wA, wB, 6); PROJSTEP(wB, wA, 7);
#undef LOADW
#undef PROJSTEP
}

// ---------------------------------------------------------------- attn ------
// grid (128, 2), block 256 = 4 waves per 16-query tile.
__global__ __launch_bounds__(256) void attn_kernel(
    const bf16* __restrict__ Qext, const bf16* __restrict__ Kext,
    const bf16* __restrict__ Vt, float* __restrict__ out) {
  // Vlds[e][256 t] bf16, 512 B rows, XOR-swizzled within row by ((e&7)<<4)
  __shared__ __align__(1024) bf16 Vlds[256 * 256];
  __shared__ __align__(16) bf16 p_lds[16][PSTR];
  __shared__ float wred[16][4], wsum[16][4], rsum_lds[16];
  int tid = threadIdx.x, wave = tid >> 6, lane = tid & 63;
  int lrow = lane & 15, lgrp = lane >> 4;
  int b = blockIdx.y;
  int s0 = blockIdx.x * 16;

  const bf16* Q = Qext + (size_t)b * REXT * EMB;
  const bf16* K = Kext + (size_t)b * REXT * EMB;
  const bf16* V = Vt + (size_t)b * 256 * REXT;

  // ---- async V stage: wave w stages e-rows [64w, 64w+64), t in [s0, s0+256).
  // LDS dest linear (base + lane*16); swizzle applied to the GLOBAL source.
  {
    int ebase = wave * 64;
    int esub = lane >> 5;            // 0/1: which of the 2 rows this instr covers
    int c = (lane & 31) * 16;        // byte offset within the 512 B row
    for (int i = 0; i < 32; i++) {
      int e = ebase + 2 * i + esub;
      int tb = c ^ ((e & 7) << 4);   // swizzled source byte-offset in row
      const bf16* src = V + (size_t)e * REXT + s0 + (tb >> 1);
      bf16* ldst = Vlds + (size_t)(ebase + 2 * i) * 256;   // wave-uniform
      __builtin_amdgcn_global_load_lds(
          (const __attribute__((address_space(1))) void*)src,
          (__attribute__((address_space(3))) void*)ldst, 16, 0, 0);
    }
  }

  // ---- Q fragments
  bf16x8 qf[8];
  const bf16* qrow = Q + (size_t)(s0 + PADP + lrow) * EMB;
#pragma unroll
  for (int kc = 0; kc < 8; kc++) qf[kc] = *(const bf16x8*)(qrow + kc * 32 + lgrp * 8);

#define LOADK(dst, tile) { const bf16* kp = K + (size_t)(s0 + (tile) * 16 + lrow) * EMB + lgrp * 8; \
  _Pragma("unroll") for (int kc = 0; kc < 8; kc++) dst[kc] = *(const bf16x8*)(kp + kc * 32); }

#define ET(dst, kf, tile) { \
  f32x4 a0 = {0.f, 0.f, 0.f, 0.f}, a1 = {0.f, 0.f, 0.f, 0.f}; \
  a0 = MFMA16(qf[0], kf[0], a0); a1 = MFMA16(qf[1], kf[1], a1); \
  a0 = MFMA16(qf[2], kf[2], a0); a1 = MFMA16(qf[3], kf[3], a1); \
  a0 = MFMA16(qf[4], kf[4], a0); a1 = MFMA16(qf[5], kf[5], a1); \
  a0 = MFMA16(qf[6], kf[6], a0); a1 = MFMA16(qf[7], kf[7], a1); \
  int t = (tile) * 16 + lrow; \
  _Pragma("unroll") for (int r = 0; r < 4; r++) { \
    int q = 4 * lgrp + r; \
    bool valid = (t >= q) && (t <= q + 256); \
    dst[r] = valid ? (a0[r] + a1[r]) * 0.0625f : -1e30f; } }

  // ---- energy: tiles {w, w+4, w+8, w+12} (+16 for wave 0), depth-3 prefetch
  bf16x8 kA[8], kB[8], kC[8];
  f32x4 m0, m1, m2, m3;
  f32x4 m4 = {-1e30f, -1e30f, -1e30f, -1e30f};
  LOADK(kA, wave);
  LOADK(kB, wave + 4);
  LOADK(kC, wave + 8);
  ET(m0, kA, wave);
  LOADK(kA, wave + 12);
  ET(m1, kB, wave + 4);
  if (wave == 0) LOADK(kB, 16);
  ET(m2, kC, wave + 8);
  ET(m3, kA, wave + 12);
  if (wave == 0) ET(m4, kB, 16);

  // ---- kc=8 tail V fragments, direct from global (latency hides under softmax)
  bf16x8 v8[4];
#pragma unroll
  for (int nt = 0; nt < 4; nt++) {
    int e = (wave * 4 + nt) * 16 + lrow;
    v8[nt] = *(const bf16x8*)(V + (size_t)e * REXT + s0 + 256 + lgrp * 8);
  }

  // ---- in-register softmax (cross-wave combine via tiny LDS tables)
  float mr[4];
#pragma unroll
  for (int r = 0; r < 4; r++) {
    float m = fmaxf(fmaxf(m0[r], m1[r]), fmaxf(m2[r], m3[r]));
    m = fmaxf(m, m4[r]);
    m = fmaxf(m, __shfl_xor(m, 1));
    m = fmaxf(m, __shfl_xor(m, 2));
    m = fmaxf(m, __shfl_xor(m, 4));
    m = fmaxf(m, __shfl_xor(m, 8));
    mr[r] = m;
  }
  if (lrow == 0) {
#pragma unroll
    for (int r = 0; r < 4; r++) wred[4 * lgrp + r][wave] = mr[r];
  }
  __syncthreads();
  float mf[4], ps[4];
#pragma unroll
  for (int r = 0; r < 4; r++) {
    int q = 4 * lgrp + r;
    mf[r] = fmaxf(fmaxf(wred[q][0], wred[q][1]), fmaxf(wred[q][2], wred[q][3]));
    ps[r] = 0.f;
  }
#define SMT(mi, i) { int t = ((i) < 4 ? (wave + 4 * (i)) : 16) * 16 + lrow; \
  _Pragma("unroll") for (int r = 0; r < 4; r++) { \
    float p = __expf(mi[r] - mf[r]); ps[r] += p; \
    p_lds[4 * lgrp + r][t] = (bf16)p; } }
  SMT(m0, 0); SMT(m1, 1); SMT(m2, 2); SMT(m3, 3);
  if (wave == 0) SMT(m4, 4);
#pragma unroll
  for (int r = 0; r < 4; r++) {
    float sv = ps[r];
    sv += __shfl_xor(sv, 1);
    sv += __shfl_xor(sv, 2);
    sv += __shfl_xor(sv, 4);
    sv += __shfl_xor(sv, 8);
    if (lrow == 0) wsum[4 * lgrp + r][wave] = sv;
  }
  p_lds[tid >> 4][272 + (tid & 15)] = (bf16)0.f;   // zero-pad t in [272,288)
  __syncthreads();
  if (tid < 16)
    rsum_lds[tid] = 1.f / (wsum[tid][0] + wsum[tid][1] + wsum[tid][2] + wsum[tid][3]);
  __syncthreads();

  // ---- PV from LDS (swizzled reads), ping-pong depth 2
  f32x4 acc[4];
#pragma unroll
  for (int nt = 0; nt < 4; nt++)
#pragma unroll
    for (int j = 0; j < 4; j++) acc[nt][j] = 0.f;

  asm volatile("s_waitcnt vmcnt(0)" ::: "memory");  // V staging complete (per-wave)

#define LOADVL(dst, kc) { _Pragma("unroll") for (int nt = 0; nt < 4; nt++) { \
    int e = (wave * 4 + nt) * 16 + lrow; \
    int byteo = e * 512 + (((kc) * 64 + lgrp * 16) ^ ((e & 7) << 4)); \
    dst[nt] = *(const bf16x8*)((const char*)Vlds + byteo); } }
#define LOADPL(dst, kc) dst = *(const bf16x8*)(&p_lds[lrow][(kc) * 32 + lgrp * 8]);
#define PVSTEP(vf, pf) { \
  acc[0] = MFMA16(pf, vf[0], acc[0]); acc[1] = MFMA16(pf, vf[1], acc[1]); \
  acc[2] = MFMA16(pf, vf[2], acc[2]); acc[3] = MFMA16(pf, vf[3], acc[3]); }

  bf16x8 vA[4], vB[4], pA, pB;
  LOADVL(vA, 0); LOADPL(pA, 0);
  LOADVL(vB, 1); LOADPL(pB, 1);
  PVSTEP(vA, pA);
  LOADVL(vA, 2); LOADPL(pA, 2);
  PVSTEP(vB, pB);
  LOADVL(vB, 3); LOADPL(pB, 3);
  PVSTEP(vA, pA);
  LOADVL(vA, 4); LOADPL(pA, 4);
  PVSTEP(vB, pB);
  LOADVL(vB, 5); LOADPL(pB, 5);
  PVSTEP(vA, pA);
  LOADVL(vA, 6); LOADPL(pA, 6);
  PVSTEP(vB, pB);
  LOADVL(vB, 7); LOADPL(pB, 7);
  PVSTEP(vA, pA);
  LOADPL(pA, 8);
  PVSTEP(vB, pB);
  PVSTEP(v8, pA);

  // ---- epilogue
  float* orow = out + ((size_t)b * SQ + s0) * EMB;
#pragma unroll
  for (int nt = 0; nt < 4; nt++) {
#pragma unroll
    for (int r = 0; r < 4; r++) {
      int q = 4 * lgrp + r;
      orow[(size_t)q * EMB + (wave * 4 + nt) * 16 + lrow] = acc[nt][r] * rsum_lds[q];
    }
  }
}

// -------------------------------------------------------------- launch ------
extern "C" void kernel_launch(void* const* d_in, const int* in_sizes, int n_in,
                              void* d_out, int out_size, void* d_ws, size_t ws_size,
                              hipStream_t stream) {
  const float* x  = (const float*)d_in[0];
  const float* Wq = (const float*)d_in[1];
  const float* bq = (const float*)d_in[2];
  const float* Wk = (const float*)d_in[3];
  const float* bk = (const float*)d_in[4];
  const float* Wv = (const float*)d_in[5];
  const float* bv = (const float*)d_in[6];
  float* out = (float*)d_out;

  char* ws = (char*)d_ws;
  bf16* W_T   = (bf16*)(ws);
  float* bias = (float*)(ws + 393216);
  bf16* Qext  = (bf16*)(ws + 396288);
  bf16* Kext  = (bf16*)(ws + 396288 + 2424832);
  bf16* Vt    = (bf16*)(ws + 396288 + 2u * 2424832);

  prep_kernel<<<49, 256, 0, stream>>>(Wq, bq, Wk, bk, Wv, bv, W_T, bias);
  proj_kernel<<<dim3(74, 6), 256, 0, stream>>>(x, W_T, bias, Qext, Kext, Vt);
  attn_kernel<<<dim3(128, 2), 256, 0, stream>>>(Qext, Kext, Vt, out);
}